// Round 3
// baseline (744.376 us; speedup 1.0000x reference)
//
#include <hip/hip_runtime.h>
#include <hip/hip_fp16.h>

// ---------------------------------------------------------------------------
// GIN (5 layers) + BN + graph pooling + MLP head.
// R18: (1) UNFUSE prep from hist -- R17's fusion regressed the atomic pipe
//      (102us vs 67+8: prep's streaming loads + cnt_graph atomics share the
//      L2/atomic queues the histogram serializes on).
//      (2) Fuse gather into mlp for layers 2-5 (k_gmlp): kills the per-layer
//      false global barrier (gather->mlp kernel boundary) and the 25.6 MB
//      aggh round trip. Wave gathers its own 16 nodes (16-deep ILP, rp
//      prefetched via shfl), parks BN'd fp16 in bank-swizzled LDS
//      (c ^ ((nt&7)<<3): b128 frag reads = 2 lanes/bank = free), feeds MFMA
//      B-frags directly. All LDS wave-private -> no barrier in gather->MFMA
//      path; gather stalls of one block overlap MFMA of another. vb/vb2
//      double-buffer (fused kernel reads all nodes while writing its tile).
//      Quantization point identical to aggh path -> absmax unchanged.
// R17: zero pooling atomics (sorted batch -> k_pool_bn segment-sum);
//      BN partials block-aggregated (128 atomic dwords/block).
// R16: per-wave 16-node C^T MFMA tiles, fp32-equiv hi/lo weight split.
// Floors (measured): k_hist 67us = 56MB atomic write-through; k_fill ~55us
// = scatter line ping-pong; gathers = fp16 + 16-deep ILP at L2/L3 floor.
// ---------------------------------------------------------------------------

#define SCAN_ELEMS 1024

typedef _Float16 half_t;
typedef half_t f16x8 __attribute__((ext_vector_type(8)));
typedef float f32x4 __attribute__((ext_vector_type(4)));

__device__ __forceinline__ unsigned short f2h(float f) {
    return __half_as_ushort(__float2half_rn(f));
}
__device__ __forceinline__ float h2f(unsigned short s) {
    return __half2float(__ushort_as_half(s));
}
__device__ __forceinline__ f32x4 mfma16(f16x8 a, f16x8 b, f32x4 c) {
    return __builtin_amdgcn_mfma_f32_16x16x32_f16(a, b, c, 0, 0, 0);
}

// Edge-only histogram + rank (atomic returns slot)
__global__ __launch_bounds__(256) void k_hist(const int* __restrict__ dst, int E,
        int* __restrict__ cnt_node, int* __restrict__ rank_) {
    int i = blockIdx.x * blockDim.x + threadIdx.x;
    if (i < E) rank_[i] = atomicAdd(&cnt_node[dst[i]], 1);
}

// Node prep: x -> fp16 padded 16ch, graph counts
__global__ __launch_bounds__(256) void k_prep(const float* __restrict__ x,
        unsigned short* __restrict__ x16h, const int* __restrict__ batch,
        int* __restrict__ cnt_graph, int N) {
    int i = blockIdx.x * blockDim.x + threadIdx.x;
    if (i < N) {
        atomicAdd(&cnt_graph[batch[i]], 1);
#pragma unroll
        for (int k = 0; k < 11; ++k) x16h[i * 16 + k] = f2h(x[i * 11 + k]);
#pragma unroll
        for (int k = 11; k < 16; ++k) x16h[i * 16 + k] = 0;
    }
}

__global__ __launch_bounds__(256) void k_scan1(const int* __restrict__ cnt, int n,
        int* __restrict__ rp, int* __restrict__ bsum) {
    __shared__ int sdata[256];
    int t = threadIdx.x;
    int base = blockIdx.x * SCAN_ELEMS + t * 4;
    int v0 = (base + 0 < n) ? cnt[base + 0] : 0;
    int v1 = (base + 1 < n) ? cnt[base + 1] : 0;
    int v2 = (base + 2 < n) ? cnt[base + 2] : 0;
    int v3 = (base + 3 < n) ? cnt[base + 3] : 0;
    int tsum = v0 + v1 + v2 + v3;
    sdata[t] = tsum;
    __syncthreads();
    for (int off = 1; off < 256; off <<= 1) {
        int val = (t >= off) ? sdata[t - off] : 0;
        __syncthreads();
        sdata[t] += val;
        __syncthreads();
    }
    int excl = sdata[t] - tsum;
    if (t == 255) bsum[blockIdx.x] = sdata[255];
    if (base + 0 < n) rp[base + 0] = excl;
    if (base + 1 < n) rp[base + 1] = excl + v0;
    if (base + 2 < n) rp[base + 2] = excl + v0 + v1;
    if (base + 3 < n) rp[base + 3] = excl + v0 + v1 + v2;
}

// block 0: scan of bsum -> boffs (nb <= 256). block 1: exclusive scan of
// cnt_graph -> gstart (graph CSR row pointers; Gn <= 1024, 4/thread).
__global__ __launch_bounds__(256) void k_scan2g(
        const int* __restrict__ bsum, int nb, int* __restrict__ boffs,
        const int* __restrict__ cntg, int Gn, int* __restrict__ gstart) {
    __shared__ int sd[256];
    int t = threadIdx.x;
    if (blockIdx.x == 0) {
        int v = (t < nb) ? bsum[t] : 0;
        sd[t] = v;
        __syncthreads();
        for (int off = 1; off < 256; off <<= 1) {
            int val = (t >= off) ? sd[t - off] : 0;
            __syncthreads();
            sd[t] += val;
            __syncthreads();
        }
        if (t < nb) boffs[t] = sd[t] - v;
    } else {
        int base = t * 4;
        int v0 = (base + 0 < Gn) ? cntg[base + 0] : 0;
        int v1 = (base + 1 < Gn) ? cntg[base + 1] : 0;
        int v2 = (base + 2 < Gn) ? cntg[base + 2] : 0;
        int v3 = (base + 3 < Gn) ? cntg[base + 3] : 0;
        int tsum = v0 + v1 + v2 + v3;
        sd[t] = tsum;
        __syncthreads();
        for (int off = 1; off < 256; off <<= 1) {
            int val = (t >= off) ? sd[t - off] : 0;
            __syncthreads();
            sd[t] += val;
            __syncthreads();
        }
        int excl = sd[t] - tsum;
        if (base + 0 < Gn) gstart[base + 0] = excl;
        if (base + 1 < Gn) gstart[base + 1] = excl + v0;
        if (base + 2 < Gn) gstart[base + 2] = excl + v0 + v1;
        if (base + 3 < Gn) gstart[base + 3] = excl + v0 + v1 + v2;
        if (t == 255) gstart[Gn] = sd[255];     // = N
    }
}

__global__ __launch_bounds__(256) void k_scan3(int* __restrict__ rp, int n,
        const int* __restrict__ boffs, int E) {
    int i = blockIdx.x * blockDim.x + threadIdx.x;
    if (i < n) rp[i] += boffs[i / SCAN_ELEMS];
    if (i == 0) rp[n] = E;
}

__global__ __launch_bounds__(256) void k_fill(const int* __restrict__ src,
        const int* __restrict__ dst, const int* __restrict__ rank_, int E,
        const int* __restrict__ rp, int* __restrict__ col) {
    int e = blockIdx.x * blockDim.x + threadIdx.x;
    if (e < E) {
        __builtin_nontemporal_store(src[e], &col[rp[dst[e]] + rank_[e]]);
    }
}

// Layer-1 gather in padded 11->16 dim fp16 space: wave = 1 node, 4 edges per
// step (16 lanes per edge), 4-deep -> 16 edges in flight. fp32 out.
__global__ __launch_bounds__(256, 8) void k_gather16(
        const unsigned short* __restrict__ x16h, float* __restrict__ h16,
        const int* __restrict__ rp, const int* __restrict__ col, int N) {
    int lane = threadIdx.x & 63, wv = threadIdx.x >> 6;
    int n = blockIdx.x * 4 + wv;
    if (n >= N) return;
    int sub = lane >> 4, c = lane & 15;
    int start = rp[n], end = rp[n + 1];
    float s0 = 0.f, s1 = 0.f, s2 = 0.f, s3 = 0.f;
    int eb = start;
    for (; eb + 16 <= end; eb += 16) {
        int j0 = col[eb + sub];
        int j1 = col[eb + 4 + sub];
        int j2 = col[eb + 8 + sub];
        int j3 = col[eb + 12 + sub];
        s0 += h2f(x16h[(size_t)j0 * 16 + c]);
        s1 += h2f(x16h[(size_t)j1 * 16 + c]);
        s2 += h2f(x16h[(size_t)j2 * 16 + c]);
        s3 += h2f(x16h[(size_t)j3 * 16 + c]);
    }
    for (; eb + 4 <= end; eb += 4) {
        int j0 = col[eb + sub];
        s0 += h2f(x16h[(size_t)j0 * 16 + c]);
    }
    for (int e = eb + sub; e < end; e += 4) {
        s1 += h2f(x16h[(size_t)col[e] * 16 + c]);
    }
    float s = (s0 + s1) + (s2 + s3);
    s += __shfl_xor(s, 16);
    s += __shfl_xor(s, 32);
    if (lane < 16) {
        h16[(size_t)n * 16 + lane] = s + h2f(x16h[(size_t)n * 16 + lane]);
    }
}

// Pack W^T into 16x16x32-f16 A-fragment layout, hi/lo split (W = hi + lo
// captures fp32 weights exactly-enough; MFMA accumulates fp32).
__global__ __launch_bounds__(256) void k_wprep(
        const float* __restrict__ W1a, const float* __restrict__ W1b,
        const float* __restrict__ Wa, const float* __restrict__ Wb,
        half_t* __restrict__ out) {
    int mat = blockIdx.x;          // 0=W1a 1=W1b 2..5=Wa[l] 6..9=Wb[l]
    const float* W; int K;
    if (mat == 0)      { W = W1a; K = 11; }
    else if (mat == 1) { W = W1b; K = 64; }
    else if (mat < 6)  { W = Wa + (mat - 2) * 4096; K = 64; }
    else               { W = Wb + (mat - 6) * 4096; K = 64; }
    int lane = threadIdx.x & 63, m = threadIdx.x >> 6;
    int row = 16 * m + (lane & 15);
#pragma unroll
    for (int ks = 0; ks < 2; ++ks) {
        f16x8 hi, lo;
#pragma unroll
        for (int j = 0; j < 8; ++j) {
            int k = 32 * ks + (lane >> 4) * 8 + j;
            float w = (k < K) ? W[k * 64 + row] : 0.f;
            half_t h = (half_t)w;
            hi[j] = h;
            lo[j] = (half_t)(w - (float)h);
        }
        size_t base = ((size_t)mat * 4 + m) * 4 + (size_t)ks * 2;
        *(f16x8*)(out + ((base + 0) * 64 + lane) * 8) = hi;
        *(f16x8*)(out + ((base + 1) * 64 + lane) * 8) = lo;
    }
}

// Layer-1 MLP: one block = one 64-node tile, 4 waves x 16 nodes each.
// Both matvecs via mfma_f32_16x16x32_f16 on C^T = W^T x H^T (wave-private).
// Phase C: fp16 store + block-aggregated BN partials.
__global__ __launch_bounds__(256, 4) void k_mlp1(
        const float* __restrict__ h16, unsigned short* __restrict__ vout,
        const half_t* __restrict__ wf1, const float* __restrict__ ba,
        const half_t* __restrict__ wf2, const float* __restrict__ bb,
        float* __restrict__ bnpart, int N) {
    __shared__ float hb[64 * 64];
    __shared__ float4 bnS[4][16], bnQ[4][16];
    float4* hb4 = (float4*)hb;
    const int tid = threadIdx.x;
    const int lane = tid & 63;
    const int wv = tid >> 6;
    const int n0 = blockIdx.x * 64;
    const int l15 = lane & 15;
    const int g = lane >> 4;
    const int nt = wv * 16 + l15;
    const int node = n0 + nt;

    f32x4 acc[4];
#pragma unroll
    for (int m = 0; m < 4; ++m) {
        float4 bv = *(const float4*)(ba + 16 * m + 4 * g);
        acc[m][0] = bv.x; acc[m][1] = bv.y; acc[m][2] = bv.z; acc[m][3] = bv.w;
    }
    // B = H^T from h16 (fp32 Nx16), hi/lo split (exact).
    f16x8 bhi, blo;
#pragma unroll
    for (int j = 0; j < 8; ++j) { bhi[j] = (half_t)0; blo[j] = (half_t)0; }
    if (g < 2 && node < N) {
        float4 v0 = *(const float4*)(h16 + (size_t)node * 16 + g * 8);
        float4 v1 = *(const float4*)(h16 + (size_t)node * 16 + g * 8 + 4);
        float v[8] = {v0.x, v0.y, v0.z, v0.w, v1.x, v1.y, v1.z, v1.w};
#pragma unroll
        for (int j = 0; j < 8; ++j) {
            half_t h = (half_t)v[j];
            bhi[j] = h;
            blo[j] = (half_t)(v[j] - (float)h);
        }
    }
#pragma unroll
    for (int m = 0; m < 4; ++m) {
        f16x8 ah = *(const f16x8*)(wf1 + (size_t)((m * 4 + 0) * 64 + lane) * 8);
        f16x8 al = *(const f16x8*)(wf1 + (size_t)((m * 4 + 1) * 64 + lane) * 8);
        acc[m] = mfma16(ah, bhi, acc[m]);
        acc[m] = mfma16(al, bhi, acc[m]);
        acc[m] = mfma16(ah, blo, acc[m]);
    }

    // relu + park C1 in the wave's private LDS slice
#pragma unroll
    for (int m = 0; m < 4; ++m) {
        int q = 4 * m + g;
        hb4[nt * 16 + (q ^ l15)] = make_float4(
            fmaxf(acc[m][0], 0.f), fmaxf(acc[m][1], 0.f),
            fmaxf(acc[m][2], 0.f), fmaxf(acc[m][3], 0.f));
    }

    // matvec2: B2 = H2^T rebuilt from LDS, hi/lo split.
    f16x8 b2h[2], b2l[2];
#pragma unroll
    for (int ks = 0; ks < 2; ++ks) {
        int q0 = 8 * ks + 2 * g;
        float4 u0 = hb4[nt * 16 + ((q0 + 0) ^ l15)];
        float4 u1 = hb4[nt * 16 + ((q0 + 1) ^ l15)];
        float v[8] = {u0.x, u0.y, u0.z, u0.w, u1.x, u1.y, u1.z, u1.w};
#pragma unroll
        for (int j = 0; j < 8; ++j) {
            half_t h = (half_t)v[j];
            b2h[ks][j] = h;
            b2l[ks][j] = (half_t)(v[j] - (float)h);
        }
    }
    f32x4 acc2[4];
#pragma unroll
    for (int m = 0; m < 4; ++m) {
        float4 bv = *(const float4*)(bb + 16 * m + 4 * g);
        acc2[m][0] = bv.x; acc2[m][1] = bv.y; acc2[m][2] = bv.z; acc2[m][3] = bv.w;
    }
#pragma unroll
    for (int m = 0; m < 4; ++m) {
#pragma unroll
        for (int ks = 0; ks < 2; ++ks) {
            f16x8 ah = *(const f16x8*)(wf2 + (size_t)((m * 4 + ks * 2 + 0) * 64 + lane) * 8);
            f16x8 al = *(const f16x8*)(wf2 + (size_t)((m * 4 + ks * 2 + 1) * 64 + lane) * 8);
            acc2[m] = mfma16(ah, b2h[ks], acc2[m]);
            acc2[m] = mfma16(al, b2h[ks], acc2[m]);
            acc2[m] = mfma16(ah, b2l[ks], acc2[m]);
        }
    }
#pragma unroll
    for (int m = 0; m < 4; ++m) {
        int q = 4 * m + g;
        hb4[nt * 16 + (q ^ l15)] = make_float4(
            fmaxf(acc2[m][0], 0.f), fmaxf(acc2[m][1], 0.f),
            fmaxf(acc2[m][2], 0.f), fmaxf(acc2[m][3], 0.f));
    }

    // ---- phase C: fp16 store + BN partial stats ----
    {
        int q = lane & 15;
        int ng = lane >> 4;
        int base_nt = wv * 16;
        float4 bs = make_float4(0, 0, 0, 0), bq = make_float4(0, 0, 0, 0);
#pragma unroll
        for (int s2 = 0; s2 < 4; ++s2) {
            int nt2 = base_nt + s2 * 4 + ng;
            int n = n0 + nt2;
            if (n < N) {
                float4 v = hb4[nt2 * 16 + (q ^ (nt2 & 15))];
                ushort4 o;
                o.x = f2h(v.x); o.y = f2h(v.y); o.z = f2h(v.z); o.w = f2h(v.w);
                *(ushort4*)(vout + (size_t)n * 64 + q * 4) = o;
                bs.x += v.x; bs.y += v.y; bs.z += v.z; bs.w += v.w;
                bq.x += v.x * v.x; bq.y += v.y * v.y;
                bq.z += v.z * v.z; bq.w += v.w * v.w;
            }
        }
#pragma unroll
        for (int off = 16; off < 64; off <<= 1) {
            bs.x += __shfl_xor(bs.x, off); bs.y += __shfl_xor(bs.y, off);
            bs.z += __shfl_xor(bs.z, off); bs.w += __shfl_xor(bs.w, off);
            bq.x += __shfl_xor(bq.x, off); bq.y += __shfl_xor(bq.y, off);
            bq.z += __shfl_xor(bq.z, off); bq.w += __shfl_xor(bq.w, off);
        }
        if (ng == 0) { bnS[wv][q] = bs; bnQ[wv][q] = bq; }
        __syncthreads();
        if (tid < 16) {
            float4 s4 = bnS[0][tid], q4 = bnQ[0][tid];
#pragma unroll
            for (int w2 = 1; w2 < 4; ++w2) {
                float4 t = bnS[w2][tid];
                s4.x += t.x; s4.y += t.y; s4.z += t.z; s4.w += t.w;
                float4 u = bnQ[w2][tid];
                q4.x += u.x; q4.y += u.y; q4.z += u.z; q4.w += u.w;
            }
            float* bkt = bnpart + (blockIdx.x & 31) * 128;
            atomicAdd(&bkt[tid * 4 + 0], s4.x);
            atomicAdd(&bkt[tid * 4 + 1], s4.y);
            atomicAdd(&bkt[tid * 4 + 2], s4.z);
            atomicAdd(&bkt[tid * 4 + 3], s4.w);
            atomicAdd(&bkt[64 + tid * 4 + 0], q4.x);
            atomicAdd(&bkt[64 + tid * 4 + 1], q4.y);
            atomicAdd(&bkt[64 + tid * 4 + 2], q4.z);
            atomicAdd(&bkt[64 + tid * 4 + 3], q4.w);
        }
    }
}

// Fused gather + MLP (layers 2-5): one block = one 64-node tile, 4 waves x
// 16 nodes. Gather phase: wave loops its 16 nodes (lane = channel, 16-deep
// edge ILP, rp prefetched via shfl), applies BN affine, parks fp16 in
// bank-swizzled LDS hs[nt][c ^ ((nt&7)<<3)]. B-frag reads (16B/lane) then
// hit 8 distinct bank quads (2 lanes each = free). All hs/hb accesses are
// wave-private -> no barrier until the BN aggregation at the end.
__global__ __launch_bounds__(256, 4) void k_gmlp(
        const unsigned short* __restrict__ vin, unsigned short* __restrict__ vout,
        const int* __restrict__ rp, const int* __restrict__ col,
        const float* __restrict__ ab_prev,
        const half_t* __restrict__ wf1, const float* __restrict__ ba,
        const half_t* __restrict__ wf2, const float* __restrict__ bb,
        float* __restrict__ bnpart, int N) {
    __shared__ unsigned short hs[64 * 64];   // gathered input, fp16, swizzled
    __shared__ float hb[64 * 64];            // C1/C2 park (phase-C layout)
    __shared__ float4 bnS[4][16], bnQ[4][16];
    float4* hb4 = (float4*)hb;
    const int tid = threadIdx.x;
    const int lane = tid & 63;
    const int wv = tid >> 6;
    const int n0 = blockIdx.x * 64;
    const int l15 = lane & 15;
    const int g = lane >> 4;

    // ---- gather phase: 16 nodes per wave, lane = channel ----
    {
        float a = ab_prev[lane];
        float b = ab_prev[64 + lane];
        // prefetch this wave's 17 rp values
        int rpl = 0;
        {
            int idx = n0 + wv * 16 + lane;
            if (lane < 17) rpl = rp[(idx <= N) ? idx : N];
        }
        for (int t = 0; t < 16; ++t) {
            int nt = wv * 16 + t;
            int n = n0 + nt;
            float h2 = 0.f;
            if (n < N) {
                int start = __shfl(rpl, t);
                int end = __shfl(rpl, t + 1);
                float s[16];
#pragma unroll
                for (int u = 0; u < 16; ++u) s[u] = 0.f;
                s[0] = h2f(vin[(size_t)n * 64 + lane]);
                int e = start;
                for (; e + 16 <= end; e += 16) {
                    int j[16];
#pragma unroll
                    for (int u = 0; u < 16; ++u) j[u] = col[e + u];
#pragma unroll
                    for (int u = 0; u < 16; ++u)
                        s[u] += h2f(vin[(size_t)j[u] * 64 + lane]);
                }
                for (; e + 4 <= end; e += 4) {
                    int j0 = col[e + 0], j1 = col[e + 1];
                    int j2 = col[e + 2], j3 = col[e + 3];
                    s[0] += h2f(vin[(size_t)j0 * 64 + lane]);
                    s[1] += h2f(vin[(size_t)j1 * 64 + lane]);
                    s[2] += h2f(vin[(size_t)j2 * 64 + lane]);
                    s[3] += h2f(vin[(size_t)j3 * 64 + lane]);
                }
                for (; e < end; ++e) s[0] += h2f(vin[(size_t)col[e] * 64 + lane]);
#pragma unroll
                for (int u = 8; u > 0; u >>= 1)
#pragma unroll
                    for (int v2 = 0; v2 < u; ++v2) s[v2] += s[v2 + u];
                h2 = fmaf(a, s[0], b * (float)(1 + end - start));
            }
            hs[nt * 64 + (lane ^ ((nt & 7) << 3))] = f2h(h2);
        }
    }
    // no barrier: each wave reads only its own 16-node hs slice below

    const int nt = wv * 16 + l15;          // B-operand col (this lane's node)

    // ---- matvec1: C1^T = W1^T x H^T; bias folded into acc init ----
    f32x4 acc[4];
#pragma unroll
    for (int m = 0; m < 4; ++m) {
        float4 bv = *(const float4*)(ba + 16 * m + 4 * g);
        acc[m][0] = bv.x; acc[m][1] = bv.y; acc[m][2] = bv.z; acc[m][3] = bv.w;
    }
    {
        // channel blocks cb = g (k 0..31) and g+4 (k 32..63), swizzled
        f16x8 b0 = *(const f16x8*)(hs + nt * 64 + ((g ^ (nt & 7)) << 3));
        f16x8 b1 = *(const f16x8*)(hs + nt * 64 + (((g + 4) ^ (nt & 7)) << 3));
#pragma unroll
        for (int m = 0; m < 4; ++m) {
            f16x8 a0h = *(const f16x8*)(wf1 + (size_t)((m * 4 + 0) * 64 + lane) * 8);
            f16x8 a0l = *(const f16x8*)(wf1 + (size_t)((m * 4 + 1) * 64 + lane) * 8);
            f16x8 a1h = *(const f16x8*)(wf1 + (size_t)((m * 4 + 2) * 64 + lane) * 8);
            f16x8 a1l = *(const f16x8*)(wf1 + (size_t)((m * 4 + 3) * 64 + lane) * 8);
            acc[m] = mfma16(a0h, b0, acc[m]);
            acc[m] = mfma16(a0l, b0, acc[m]);
            acc[m] = mfma16(a1h, b1, acc[m]);
            acc[m] = mfma16(a1l, b1, acc[m]);
        }
    }

    // relu + park C1 in the wave's private LDS slice (phase-C swizzle)
#pragma unroll
    for (int m = 0; m < 4; ++m) {
        int q = 4 * m + g;
        hb4[nt * 16 + (q ^ l15)] = make_float4(
            fmaxf(acc[m][0], 0.f), fmaxf(acc[m][1], 0.f),
            fmaxf(acc[m][2], 0.f), fmaxf(acc[m][3], 0.f));
    }

    // ---- matvec2: B2 = H2^T rebuilt from LDS, hi/lo split ----
    f16x8 b2h[2], b2l[2];
#pragma unroll
    for (int ks = 0; ks < 2; ++ks) {
        int q0 = 8 * ks + 2 * g;
        float4 u0 = hb4[nt * 16 + ((q0 + 0) ^ l15)];
        float4 u1 = hb4[nt * 16 + ((q0 + 1) ^ l15)];
        float v[8] = {u0.x, u0.y, u0.z, u0.w, u1.x, u1.y, u1.z, u1.w};
#pragma unroll
        for (int j = 0; j < 8; ++j) {
            half_t h = (half_t)v[j];
            b2h[ks][j] = h;
            b2l[ks][j] = (half_t)(v[j] - (float)h);
        }
    }
    f32x4 acc2[4];
#pragma unroll
    for (int m = 0; m < 4; ++m) {
        float4 bv = *(const float4*)(bb + 16 * m + 4 * g);
        acc2[m][0] = bv.x; acc2[m][1] = bv.y; acc2[m][2] = bv.z; acc2[m][3] = bv.w;
    }
#pragma unroll
    for (int m = 0; m < 4; ++m) {
#pragma unroll
        for (int ks = 0; ks < 2; ++ks) {
            f16x8 ah = *(const f16x8*)(wf2 + (size_t)((m * 4 + ks * 2 + 0) * 64 + lane) * 8);
            f16x8 al = *(const f16x8*)(wf2 + (size_t)((m * 4 + ks * 2 + 1) * 64 + lane) * 8);
            acc2[m] = mfma16(ah, b2h[ks], acc2[m]);
            acc2[m] = mfma16(al, b2h[ks], acc2[m]);
            acc2[m] = mfma16(ah, b2l[ks], acc2[m]);
        }
    }
#pragma unroll
    for (int m = 0; m < 4; ++m) {
        int q = 4 * m + g;
        hb4[nt * 16 + (q ^ l15)] = make_float4(
            fmaxf(acc2[m][0], 0.f), fmaxf(acc2[m][1], 0.f),
            fmaxf(acc2[m][2], 0.f), fmaxf(acc2[m][3], 0.f));
    }

    // ---- phase C: fp16 store + BN partial stats ----
    {
        int q = lane & 15;
        int ng = lane >> 4;
        int base_nt = wv * 16;
        float4 bs = make_float4(0, 0, 0, 0), bq = make_float4(0, 0, 0, 0);
#pragma unroll
        for (int s2 = 0; s2 < 4; ++s2) {
            int nt2 = base_nt + s2 * 4 + ng;
            int n = n0 + nt2;
            if (n < N) {
                float4 v = hb4[nt2 * 16 + (q ^ (nt2 & 15))];
                ushort4 o;
                o.x = f2h(v.x); o.y = f2h(v.y); o.z = f2h(v.z); o.w = f2h(v.w);
                *(ushort4*)(vout + (size_t)n * 64 + q * 4) = o;
                bs.x += v.x; bs.y += v.y; bs.z += v.z; bs.w += v.w;
                bq.x += v.x * v.x; bq.y += v.y * v.y;
                bq.z += v.z * v.z; bq.w += v.w * v.w;
            }
        }
#pragma unroll
        for (int off = 16; off < 64; off <<= 1) {
            bs.x += __shfl_xor(bs.x, off); bs.y += __shfl_xor(bs.y, off);
            bs.z += __shfl_xor(bs.z, off); bs.w += __shfl_xor(bs.w, off);
            bq.x += __shfl_xor(bq.x, off); bq.y += __shfl_xor(bq.y, off);
            bq.z += __shfl_xor(bq.z, off); bq.w += __shfl_xor(bq.w, off);
        }
        if (ng == 0) { bnS[wv][q] = bs; bnQ[wv][q] = bq; }
        __syncthreads();
        if (tid < 16) {
            float4 s4 = bnS[0][tid], q4 = bnQ[0][tid];
#pragma unroll
            for (int w2 = 1; w2 < 4; ++w2) {
                float4 t = bnS[w2][tid];
                s4.x += t.x; s4.y += t.y; s4.z += t.z; s4.w += t.w;
                float4 u = bnQ[w2][tid];
                q4.x += u.x; q4.y += u.y; q4.z += u.z; q4.w += u.w;
            }
            float* bkt = bnpart + (blockIdx.x & 31) * 128;
            atomicAdd(&bkt[tid * 4 + 0], s4.x);
            atomicAdd(&bkt[tid * 4 + 1], s4.y);
            atomicAdd(&bkt[tid * 4 + 2], s4.z);
            atomicAdd(&bkt[tid * 4 + 3], s4.w);
            atomicAdd(&bkt[64 + tid * 4 + 0], q4.x);
            atomicAdd(&bkt[64 + tid * 4 + 1], q4.y);
            atomicAdd(&bkt[64 + tid * 4 + 2], q4.z);
            atomicAdd(&bkt[64 + tid * 4 + 3], q4.w);
        }
    }
}

// Graph pooling (contiguous segment-sum, zero atomics) + BN finalize.
__global__ __launch_bounds__(256) void k_pool_bn(
        const unsigned short* __restrict__ vb, const int* __restrict__ gstart,
        float* __restrict__ Sg,
        const float* __restrict__ bnpart, const float* __restrict__ gamma,
        const float* __restrict__ beta, float* __restrict__ a_out,
        float* __restrict__ b_out, int N, int Gn, int nbp) {
    if ((int)blockIdx.x == nbp) {
        int c = threadIdx.x;
        if (c < 64) {
            float s = 0.f, q = 0.f;
            for (int i = 0; i < 32; ++i) {
                s += bnpart[i * 128 + c];
                q += bnpart[i * 128 + 64 + c];
            }
            float invN = 1.0f / (float)N;
            float mu = s * invN;
            float var = q * invN - mu * mu;
            float ac = gamma[c] * rsqrtf(var + 1e-5f);
            a_out[c] = ac;
            b_out[c] = beta[c] - mu * ac;
        }
        return;
    }
    int lane = threadIdx.x & 63, wv = threadIdx.x >> 6;
    int g = blockIdx.x * 4 + wv;
    if (g >= Gn) return;
    int sub = lane >> 4, q = lane & 15;
    int s = gstart[g], e = gstart[g + 1];
    float4 a0 = make_float4(0, 0, 0, 0), a1 = make_float4(0, 0, 0, 0);
    float4 a2 = make_float4(0, 0, 0, 0), a3 = make_float4(0, 0, 0, 0);
    int eb = s;
    for (; eb + 16 <= e; eb += 16) {
        ushort4 u0 = *(const ushort4*)(vb + (size_t)(eb + 0 + sub) * 64 + q * 4);
        ushort4 u1 = *(const ushort4*)(vb + (size_t)(eb + 4 + sub) * 64 + q * 4);
        ushort4 u2 = *(const ushort4*)(vb + (size_t)(eb + 8 + sub) * 64 + q * 4);
        ushort4 u3 = *(const ushort4*)(vb + (size_t)(eb + 12 + sub) * 64 + q * 4);
        a0.x += h2f(u0.x); a0.y += h2f(u0.y); a0.z += h2f(u0.z); a0.w += h2f(u0.w);
        a1.x += h2f(u1.x); a1.y += h2f(u1.y); a1.z += h2f(u1.z); a1.w += h2f(u1.w);
        a2.x += h2f(u2.x); a2.y += h2f(u2.y); a2.z += h2f(u2.z); a2.w += h2f(u2.w);
        a3.x += h2f(u3.x); a3.y += h2f(u3.y); a3.z += h2f(u3.z); a3.w += h2f(u3.w);
    }
    for (; eb + 4 <= e; eb += 4) {
        ushort4 u0 = *(const ushort4*)(vb + (size_t)(eb + sub) * 64 + q * 4);
        a0.x += h2f(u0.x); a0.y += h2f(u0.y); a0.z += h2f(u0.z); a0.w += h2f(u0.w);
    }
    if (eb + sub < e) {
        ushort4 u0 = *(const ushort4*)(vb + (size_t)(eb + sub) * 64 + q * 4);
        a1.x += h2f(u0.x); a1.y += h2f(u0.y); a1.z += h2f(u0.z); a1.w += h2f(u0.w);
    }
    float4 t;
    t.x = (a0.x + a1.x) + (a2.x + a3.x);
    t.y = (a0.y + a1.y) + (a2.y + a3.y);
    t.z = (a0.z + a1.z) + (a2.z + a3.z);
    t.w = (a0.w + a1.w) + (a2.w + a3.w);
#pragma unroll
    for (int off = 16; off < 64; off <<= 1) {
        t.x += __shfl_xor(t.x, off); t.y += __shfl_xor(t.y, off);
        t.z += __shfl_xor(t.z, off); t.w += __shfl_xor(t.w, off);
    }
    if (sub == 0) {
        *(float4*)(Sg + (size_t)g * 64 + q * 4) = t;
    }
}

// Head: z[g,320] = concat_l (a_l*S_l[g] + b_l*cnt[g]); out = relu(z@fc1+b)@fc2+b
__global__ __launch_bounds__(256) void k_final(
        const float* __restrict__ S, const float* __restrict__ ab,
        const int* __restrict__ cntg,
        const float* __restrict__ fc1W, const float* __restrict__ fc1b,
        const float* __restrict__ fc2W, const float* __restrict__ fc2b,
        float* __restrict__ out, int G) {
    __shared__ float zbuf[4][320];
    int tid = threadIdx.x;
    int lane = tid & 63, wv = tid >> 6;
    int g = blockIdx.x * 4 + wv;
    if (g >= G) return;
    float cf = (float)cntg[g];
#pragma unroll
    for (int l = 0; l < 5; ++l) {
        float a = ab[l * 128 + lane];
        float b = ab[l * 128 + 64 + lane];
        zbuf[wv][l * 64 + lane] = a * S[((size_t)l * G + g) * 64 + lane] + b * cf;
    }
    float acc = fc1b[lane];
    for (int k = 0; k < 320; ++k) acc += zbuf[wv][k] * fc1W[k * 64 + lane];
    float t = fmaxf(acc, 0.f);
    float r = t * fc2W[lane];
#pragma unroll
    for (int off = 32; off >= 1; off >>= 1) r += __shfl_xor(r, off);
    if (lane == 0) out[g] = r + fc2b[0];
}

extern "C" void kernel_launch(void* const* d_in, const int* in_sizes, int n_in,
                              void* d_out, int out_size, void* d_ws, size_t ws_size,
                              hipStream_t stream) {
    const float* x    = (const float*)d_in[0];
    const int*   ei   = (const int*)d_in[1];
    const int*   batch= (const int*)d_in[2];
    const float* W1a  = (const float*)d_in[3];
    const float* b1a  = (const float*)d_in[4];
    const float* W1b  = (const float*)d_in[5];
    const float* b1b  = (const float*)d_in[6];
    const float* Wa   = (const float*)d_in[7];
    const float* ba   = (const float*)d_in[8];
    const float* Wb   = (const float*)d_in[9];
    const float* bb   = (const float*)d_in[10];
    const float* gamma= (const float*)d_in[11];
    const float* beta = (const float*)d_in[12];
    const float* fc1W = (const float*)d_in[13];
    const float* fc1b = (const float*)d_in[14];
    const float* fc2W = (const float*)d_in[15];
    const float* fc2b = (const float*)d_in[16];

    const int N = in_sizes[2];
    const int E = in_sizes[1] / 2;
    const int G = out_size;
    const int* srcp = ei;
    const int* dstp = ei + E;

    char* p = (char*)d_ws;
    auto alloc = [&](size_t bytes) {
        char* r = p;
        p += (bytes + 255) & ~size_t(255);
        return r;
    };
    unsigned short* vb   = (unsigned short*)alloc((size_t)N * 64 * 2);
    unsigned short* vb2  = (unsigned short*)alloc((size_t)N * 64 * 2);
    int*   col    = (int*)  alloc((size_t)E * 4);
    int*   rank_  = (int*)  alloc((size_t)E * 4);
    int*   rp     = (int*)  alloc((size_t)(N + 1) * 4);
    unsigned short* x16h = (unsigned short*)alloc((size_t)N * 16 * 2);
    float* h16    = (float*)alloc((size_t)N * 16 * 4);
    int*   bsum   = (int*)  alloc(512);
    int*   boffs  = (int*)  alloc(512);
    int*   gstart = (int*)  alloc((size_t)(G + 1) * 4);
    float* ab     = (float*)alloc(5 * 128 * 4);
    half_t* wfrag = (half_t*)alloc((size_t)10 * 8192 * 2);
    // ---- zeroed region (single memset) ----
    char*  z0     = p;
    int*   cntn   = (int*)  alloc((size_t)N * 4);
    int*   cntg   = (int*)  alloc((size_t)G * 4);
    float* S      = (float*)alloc((size_t)5 * G * 64 * 4);
    float* bnpart = (float*)alloc((size_t)5 * 32 * 128 * 4);
    size_t zbytes = (size_t)(p - z0);

    hipMemsetAsync(z0, 0, zbytes, stream);

    int nb_e = (E + 255) / 256;
    int nb_n = (N + 255) / 256;
    int nb_scan = (N + SCAN_ELEMS - 1) / SCAN_ELEMS;
    k_wprep<<<10, 256, 0, stream>>>(W1a, W1b, Wa, Wb, wfrag);
    k_hist<<<nb_e, 256, 0, stream>>>(dstp, E, cntn, rank_);
    k_prep<<<nb_n, 256, 0, stream>>>(x, x16h, batch, cntg, N);
    k_scan1<<<nb_scan, 256, 0, stream>>>(cntn, N, rp, bsum);
    k_scan2g<<<2, 256, 0, stream>>>(bsum, nb_scan, boffs, cntg, G, gstart);
    k_scan3<<<(N + 255) / 256, 256, 0, stream>>>(rp, N, boffs, E);
    k_fill<<<nb_e, 256, 0, stream>>>(srcp, dstp, rank_, E, rp, col);

    int nb_node = (N + 3) / 4;
    int nb_tile = (N + 63) / 64;
    int nbp = (G + 3) / 4;
    const size_t FR = 8192;   // halfs per packed matrix

    // Layer 1: 16-dim fp16 gather, then mlp1 does W1a from h16 (fp32)
    k_gather16<<<nb_node, 256, 0, stream>>>(x16h, h16, rp, col, N);
    k_mlp1<<<nb_tile, 256, 0, stream>>>(h16, vb,
        wfrag + 0 * FR, b1a, wfrag + 1 * FR, b1b, bnpart, N);
    k_pool_bn<<<nbp + 1, 256, 0, stream>>>(vb, gstart, S, bnpart,
        gamma, beta, ab, ab + 64, N, G, nbp);

    // Layers 2-5: fused gather+mlp, ping-pong vb <-> vb2
    unsigned short* cur = vb;
    unsigned short* nxt = vb2;
    for (int l = 0; l < 4; ++l) {
        k_gmlp<<<nb_tile, 256, 0, stream>>>(cur, nxt, rp, col,
            ab + l * 128,
            wfrag + (size_t)(2 + l) * FR, ba + l * 64,
            wfrag + (size_t)(6 + l) * FR, bb + l * 64,
            bnpart + (size_t)(l + 1) * 32 * 128, N);
        k_pool_bn<<<nbp + 1, 256, 0, stream>>>(nxt, gstart,
            S + (size_t)(l + 1) * G * 64,
            bnpart + (size_t)(l + 1) * 32 * 128,
            gamma + (l + 1) * 64, beta + (l + 1) * 64,
            ab + (l + 1) * 128, ab + (l + 1) * 128 + 64, N, G, nbp);
        unsigned short* tmp = cur; cur = nxt; nxt = tmp;
    }

    k_final<<<(G + 3) / 4, 256, 0, stream>>>(S, ab, cntg, fc1W, fc1b, fc2W, fc2b,
                                             (float*)d_out, G);
}

// Round 5
// 650.992 us; speedup vs baseline: 1.1434x; 1.1434x over previous
//
#include <hip/hip_runtime.h>
#include <hip/hip_fp16.h>

// ---------------------------------------------------------------------------
// GIN (5 layers) + BN + graph pooling + MLP head.
// R20: resubmit of R19 (bench infra failure: container died twice, no data).
// R19: revert R18's k_gmlp (regressed: occupancy 36%, sequential 16-node
//      gather per wave halved memory-level parallelism on the latency-bound
//      L2-miss gather path -- 103us vs 50+18 separate; FETCH 80MB/dispatch
//      shows the random 128B-row walk misses per-XCD L2 hard, so MLP is
//      everything). Keep R18's good piece: k_hist and k_prep UNFUSED
//      (R17's fusion contended the atomic pipe: 102us vs 67+8).
//      = R17 structure (638us) minus its one regression -> expect ~610us.
// R17: zero pooling atomics (sorted batch -> k_pool_bn segment-sum);
//      BN partials block-aggregated (128 atomic dwords/block).
// R16: per-wave 16-node C^T MFMA tiles, fp32-equiv hi/lo weight split.
// Floors (measured): k_hist 67us = 56MB atomic write-through; k_fill ~55us
// = scatter line ping-pong; gathers = 16-deep ILP at L2-miss latency floor
// (needs ~max occupancy -- do NOT fuse anything into the gather).
// ---------------------------------------------------------------------------

#define SCAN_ELEMS 1024

typedef _Float16 half_t;
typedef half_t f16x8 __attribute__((ext_vector_type(8)));
typedef float f32x4 __attribute__((ext_vector_type(4)));

__device__ __forceinline__ unsigned short f2h(float f) {
    return __half_as_ushort(__float2half_rn(f));
}
__device__ __forceinline__ float h2f(unsigned short s) {
    return __half2float(__ushort_as_half(s));
}
__device__ __forceinline__ f32x4 mfma16(f16x8 a, f16x8 b, f32x4 c) {
    return __builtin_amdgcn_mfma_f32_16x16x32_f16(a, b, c, 0, 0, 0);
}

// Edge-only histogram + rank (atomic returns slot)
__global__ __launch_bounds__(256) void k_hist(const int* __restrict__ dst, int E,
        int* __restrict__ cnt_node, int* __restrict__ rank_) {
    int i = blockIdx.x * blockDim.x + threadIdx.x;
    if (i < E) rank_[i] = atomicAdd(&cnt_node[dst[i]], 1);
}

// Node prep: x -> fp16 padded 16ch, graph counts
__global__ __launch_bounds__(256) void k_prep(const float* __restrict__ x,
        unsigned short* __restrict__ x16h, const int* __restrict__ batch,
        int* __restrict__ cnt_graph, int N) {
    int i = blockIdx.x * blockDim.x + threadIdx.x;
    if (i < N) {
        atomicAdd(&cnt_graph[batch[i]], 1);
#pragma unroll
        for (int k = 0; k < 11; ++k) x16h[i * 16 + k] = f2h(x[i * 11 + k]);
#pragma unroll
        for (int k = 11; k < 16; ++k) x16h[i * 16 + k] = 0;
    }
}

__global__ __launch_bounds__(256) void k_scan1(const int* __restrict__ cnt, int n,
        int* __restrict__ rp, int* __restrict__ bsum) {
    __shared__ int sdata[256];
    int t = threadIdx.x;
    int base = blockIdx.x * SCAN_ELEMS + t * 4;
    int v0 = (base + 0 < n) ? cnt[base + 0] : 0;
    int v1 = (base + 1 < n) ? cnt[base + 1] : 0;
    int v2 = (base + 2 < n) ? cnt[base + 2] : 0;
    int v3 = (base + 3 < n) ? cnt[base + 3] : 0;
    int tsum = v0 + v1 + v2 + v3;
    sdata[t] = tsum;
    __syncthreads();
    for (int off = 1; off < 256; off <<= 1) {
        int val = (t >= off) ? sdata[t - off] : 0;
        __syncthreads();
        sdata[t] += val;
        __syncthreads();
    }
    int excl = sdata[t] - tsum;
    if (t == 255) bsum[blockIdx.x] = sdata[255];
    if (base + 0 < n) rp[base + 0] = excl;
    if (base + 1 < n) rp[base + 1] = excl + v0;
    if (base + 2 < n) rp[base + 2] = excl + v0 + v1;
    if (base + 3 < n) rp[base + 3] = excl + v0 + v1 + v2;
}

// block 0: scan of bsum -> boffs (nb <= 256). block 1: exclusive scan of
// cnt_graph -> gstart (graph CSR row pointers; Gn <= 1024, 4/thread).
__global__ __launch_bounds__(256) void k_scan2g(
        const int* __restrict__ bsum, int nb, int* __restrict__ boffs,
        const int* __restrict__ cntg, int Gn, int* __restrict__ gstart) {
    __shared__ int sd[256];
    int t = threadIdx.x;
    if (blockIdx.x == 0) {
        int v = (t < nb) ? bsum[t] : 0;
        sd[t] = v;
        __syncthreads();
        for (int off = 1; off < 256; off <<= 1) {
            int val = (t >= off) ? sd[t - off] : 0;
            __syncthreads();
            sd[t] += val;
            __syncthreads();
        }
        if (t < nb) boffs[t] = sd[t] - v;
    } else {
        int base = t * 4;
        int v0 = (base + 0 < Gn) ? cntg[base + 0] : 0;
        int v1 = (base + 1 < Gn) ? cntg[base + 1] : 0;
        int v2 = (base + 2 < Gn) ? cntg[base + 2] : 0;
        int v3 = (base + 3 < Gn) ? cntg[base + 3] : 0;
        int tsum = v0 + v1 + v2 + v3;
        sd[t] = tsum;
        __syncthreads();
        for (int off = 1; off < 256; off <<= 1) {
            int val = (t >= off) ? sd[t - off] : 0;
            __syncthreads();
            sd[t] += val;
            __syncthreads();
        }
        int excl = sd[t] - tsum;
        if (base + 0 < Gn) gstart[base + 0] = excl;
        if (base + 1 < Gn) gstart[base + 1] = excl + v0;
        if (base + 2 < Gn) gstart[base + 2] = excl + v0 + v1;
        if (base + 3 < Gn) gstart[base + 3] = excl + v0 + v1 + v2;
        if (t == 255) gstart[Gn] = sd[255];     // = N
    }
}

__global__ __launch_bounds__(256) void k_scan3(int* __restrict__ rp, int n,
        const int* __restrict__ boffs, int E) {
    int i = blockIdx.x * blockDim.x + threadIdx.x;
    if (i < n) rp[i] += boffs[i / SCAN_ELEMS];
    if (i == 0) rp[n] = E;
}

__global__ __launch_bounds__(256) void k_fill(const int* __restrict__ src,
        const int* __restrict__ dst, const int* __restrict__ rank_, int E,
        const int* __restrict__ rp, int* __restrict__ col) {
    int e = blockIdx.x * blockDim.x + threadIdx.x;
    if (e < E) {
        __builtin_nontemporal_store(src[e], &col[rp[dst[e]] + rank_[e]]);
    }
}

// Layer-1 gather in padded 11->16 dim fp16 space: wave = 1 node, 4 edges per
// step (16 lanes per edge), 4-deep -> 16 edges in flight. fp32 out.
__global__ __launch_bounds__(256, 8) void k_gather16(
        const unsigned short* __restrict__ x16h, float* __restrict__ h16,
        const int* __restrict__ rp, const int* __restrict__ col, int N) {
    int lane = threadIdx.x & 63, wv = threadIdx.x >> 6;
    int n = blockIdx.x * 4 + wv;
    if (n >= N) return;
    int sub = lane >> 4, c = lane & 15;
    int start = rp[n], end = rp[n + 1];
    float s0 = 0.f, s1 = 0.f, s2 = 0.f, s3 = 0.f;
    int eb = start;
    for (; eb + 16 <= end; eb += 16) {
        int j0 = col[eb + sub];
        int j1 = col[eb + 4 + sub];
        int j2 = col[eb + 8 + sub];
        int j3 = col[eb + 12 + sub];
        s0 += h2f(x16h[(size_t)j0 * 16 + c]);
        s1 += h2f(x16h[(size_t)j1 * 16 + c]);
        s2 += h2f(x16h[(size_t)j2 * 16 + c]);
        s3 += h2f(x16h[(size_t)j3 * 16 + c]);
    }
    for (; eb + 4 <= end; eb += 4) {
        int j0 = col[eb + sub];
        s0 += h2f(x16h[(size_t)j0 * 16 + c]);
    }
    for (int e = eb + sub; e < end; e += 4) {
        s1 += h2f(x16h[(size_t)col[e] * 16 + c]);
    }
    float s = (s0 + s1) + (s2 + s3);
    s += __shfl_xor(s, 16);
    s += __shfl_xor(s, 32);
    if (lane < 16) {
        h16[(size_t)n * 16 + lane] = s + h2f(x16h[(size_t)n * 16 + lane]);
    }
}

// Gather (layers 2-5): one wave per node, lane = channel, fp16 in/out.
// s = v_n + sum_j v_j; h2 = a*s + b*(1+deg) in fp32; 16-deep load ILP.
__global__ __launch_bounds__(256, 8) void k_gather(
        const unsigned short* __restrict__ vin, unsigned short* __restrict__ aggh,
        const int* __restrict__ rp, const int* __restrict__ col,
        const float* __restrict__ ab_prev, int N) {
    int lane = threadIdx.x & 63, wv = threadIdx.x >> 6;
    int n = blockIdx.x * 4 + wv;
    if (n >= N) return;
    float a = ab_prev[lane];
    float b = ab_prev[64 + lane];
    int start = rp[n], end = rp[n + 1];
    float s[16];
#pragma unroll
    for (int u = 0; u < 16; ++u) s[u] = 0.f;
    s[0] = h2f(vin[(size_t)n * 64 + lane]);
    int e = start;
    for (; e + 16 <= end; e += 16) {
        int j[16];
#pragma unroll
        for (int u = 0; u < 16; ++u) j[u] = col[e + u];
#pragma unroll
        for (int u = 0; u < 16; ++u)
            s[u] += h2f(vin[(size_t)j[u] * 64 + lane]);
    }
    for (; e + 4 <= end; e += 4) {
        int j0 = col[e + 0], j1 = col[e + 1], j2 = col[e + 2], j3 = col[e + 3];
        s[0] += h2f(vin[(size_t)j0 * 64 + lane]);
        s[1] += h2f(vin[(size_t)j1 * 64 + lane]);
        s[2] += h2f(vin[(size_t)j2 * 64 + lane]);
        s[3] += h2f(vin[(size_t)j3 * 64 + lane]);
    }
    for (; e < end; ++e) s[0] += h2f(vin[(size_t)col[e] * 64 + lane]);
#pragma unroll
    for (int u = 8; u > 0; u >>= 1)
#pragma unroll
        for (int v2 = 0; v2 < u; ++v2) s[v2] += s[v2 + u];
    float h2 = fmaf(a, s[0], b * (float)(1 + end - start));
    aggh[(size_t)n * 64 + lane] = f2h(h2);
}

// Pack W^T into 16x16x32-f16 A-fragment layout, hi/lo split (W = hi + lo
// captures fp32 weights exactly-enough; MFMA accumulates fp32).
__global__ __launch_bounds__(256) void k_wprep(
        const float* __restrict__ W1a, const float* __restrict__ W1b,
        const float* __restrict__ Wa, const float* __restrict__ Wb,
        half_t* __restrict__ out) {
    int mat = blockIdx.x;          // 0=W1a 1=W1b 2..5=Wa[l] 6..9=Wb[l]
    const float* W; int K;
    if (mat == 0)      { W = W1a; K = 11; }
    else if (mat == 1) { W = W1b; K = 64; }
    else if (mat < 6)  { W = Wa + (mat - 2) * 4096; K = 64; }
    else               { W = Wb + (mat - 6) * 4096; K = 64; }
    int lane = threadIdx.x & 63, m = threadIdx.x >> 6;
    int row = 16 * m + (lane & 15);
#pragma unroll
    for (int ks = 0; ks < 2; ++ks) {
        f16x8 hi, lo;
#pragma unroll
        for (int j = 0; j < 8; ++j) {
            int k = 32 * ks + (lane >> 4) * 8 + j;
            float w = (k < K) ? W[k * 64 + row] : 0.f;
            half_t h = (half_t)w;
            hi[j] = h;
            lo[j] = (half_t)(w - (float)h);
        }
        size_t base = ((size_t)mat * 4 + m) * 4 + (size_t)ks * 2;
        *(f16x8*)(out + ((base + 0) * 64 + lane) * 8) = hi;
        *(f16x8*)(out + ((base + 1) * 64 + lane) * 8) = lo;
    }
}

// MLP: one block = one 64-node tile, 4 waves x 16 nodes each. Both matvecs
// via mfma_f32_16x16x32_f16 on C^T = W^T x H^T (wave-private, barrier-free).
// Phase C: fp16 store + block-aggregated BN partials (128 atomics/block).
template <bool FIRST>
__global__ __launch_bounds__(256, 4) void k_mlp(
        const void* __restrict__ aggp, unsigned short* __restrict__ vout,
        const half_t* __restrict__ wf1, const float* __restrict__ ba,
        const half_t* __restrict__ wf2, const float* __restrict__ bb,
        float* __restrict__ bnpart, int N) {
    __shared__ float hb[64 * 64];
    __shared__ float4 bnS[4][16], bnQ[4][16];
    float4* hb4 = (float4*)hb;
    const int tid = threadIdx.x;
    const int lane = tid & 63;
    const int wv = tid >> 6;
    const int n0 = blockIdx.x * 64;
    const int l15 = lane & 15;
    const int g = lane >> 4;
    const int nt = wv * 16 + l15;          // tile-local node (B-operand col)
    const int node = n0 + nt;

    // ---- matvec1: C1^T[ch_out][node]; bias folded into acc init.
    f32x4 acc[4];
#pragma unroll
    for (int m = 0; m < 4; ++m) {
        float4 bv = *(const float4*)(ba + 16 * m + 4 * g);
        acc[m][0] = bv.x; acc[m][1] = bv.y; acc[m][2] = bv.z; acc[m][3] = bv.w;
    }

    if (FIRST) {
        // B = H^T from h16 (fp32 Nx16), hi/lo split (exact).
        f16x8 bhi, blo;
#pragma unroll
        for (int j = 0; j < 8; ++j) { bhi[j] = (half_t)0; blo[j] = (half_t)0; }
        if (g < 2 && node < N) {
            const float* h16 = (const float*)aggp;
            float4 v0 = *(const float4*)(h16 + (size_t)node * 16 + g * 8);
            float4 v1 = *(const float4*)(h16 + (size_t)node * 16 + g * 8 + 4);
            float v[8] = {v0.x, v0.y, v0.z, v0.w, v1.x, v1.y, v1.z, v1.w};
#pragma unroll
            for (int j = 0; j < 8; ++j) {
                half_t h = (half_t)v[j];
                bhi[j] = h;
                blo[j] = (half_t)(v[j] - (float)h);
            }
        }
#pragma unroll
        for (int m = 0; m < 4; ++m) {
            f16x8 ah = *(const f16x8*)(wf1 + (size_t)((m * 4 + 0) * 64 + lane) * 8);
            f16x8 al = *(const f16x8*)(wf1 + (size_t)((m * 4 + 1) * 64 + lane) * 8);
            acc[m] = mfma16(ah, bhi, acc[m]);
            acc[m] = mfma16(al, bhi, acc[m]);
            acc[m] = mfma16(ah, blo, acc[m]);
        }
    } else {
        // B = H^T from aggh (fp16 Nx64): 16B contiguous per lane per k-step.
        f16x8 b0, b1;
#pragma unroll
        for (int j = 0; j < 8; ++j) { b0[j] = (half_t)0; b1[j] = (half_t)0; }
        if (node < N) {
            const half_t* ah16 = (const half_t*)aggp;
            b0 = *(const f16x8*)(ah16 + (size_t)node * 64 + g * 8);
            b1 = *(const f16x8*)(ah16 + (size_t)node * 64 + 32 + g * 8);
        }
#pragma unroll
        for (int m = 0; m < 4; ++m) {
            f16x8 a0h = *(const f16x8*)(wf1 + (size_t)((m * 4 + 0) * 64 + lane) * 8);
            f16x8 a0l = *(const f16x8*)(wf1 + (size_t)((m * 4 + 1) * 64 + lane) * 8);
            f16x8 a1h = *(const f16x8*)(wf1 + (size_t)((m * 4 + 2) * 64 + lane) * 8);
            f16x8 a1l = *(const f16x8*)(wf1 + (size_t)((m * 4 + 3) * 64 + lane) * 8);
            acc[m] = mfma16(a0h, b0, acc[m]);
            acc[m] = mfma16(a0l, b0, acc[m]);
            acc[m] = mfma16(a1h, b1, acc[m]);
            acc[m] = mfma16(a1l, b1, acc[m]);
        }
    }

    // relu + park C1 in the wave's private LDS slice (phase-C swizzle).
#pragma unroll
    for (int m = 0; m < 4; ++m) {
        int q = 4 * m + g;
        hb4[nt * 16 + (q ^ l15)] = make_float4(
            fmaxf(acc[m][0], 0.f), fmaxf(acc[m][1], 0.f),
            fmaxf(acc[m][2], 0.f), fmaxf(acc[m][3], 0.f));
    }
    // (no barrier: wave-private slice)

    // ---- matvec2: B2 = H2^T rebuilt from LDS, hi/lo split.
    f16x8 b2h[2], b2l[2];
#pragma unroll
    for (int ks = 0; ks < 2; ++ks) {
        int q0 = 8 * ks + 2 * g;
        float4 u0 = hb4[nt * 16 + ((q0 + 0) ^ l15)];
        float4 u1 = hb4[nt * 16 + ((q0 + 1) ^ l15)];
        float v[8] = {u0.x, u0.y, u0.z, u0.w, u1.x, u1.y, u1.z, u1.w};
#pragma unroll
        for (int j = 0; j < 8; ++j) {
            half_t h = (half_t)v[j];
            b2h[ks][j] = h;
            b2l[ks][j] = (half_t)(v[j] - (float)h);
        }
    }
    f32x4 acc2[4];
#pragma unroll
    for (int m = 0; m < 4; ++m) {
        float4 bv = *(const float4*)(bb + 16 * m + 4 * g);
        acc2[m][0] = bv.x; acc2[m][1] = bv.y; acc2[m][2] = bv.z; acc2[m][3] = bv.w;
    }
#pragma unroll
    for (int m = 0; m < 4; ++m) {
#pragma unroll
        for (int ks = 0; ks < 2; ++ks) {
            f16x8 ah = *(const f16x8*)(wf2 + (size_t)((m * 4 + ks * 2 + 0) * 64 + lane) * 8);
            f16x8 al = *(const f16x8*)(wf2 + (size_t)((m * 4 + ks * 2 + 1) * 64 + lane) * 8);
            acc2[m] = mfma16(ah, b2h[ks], acc2[m]);
            acc2[m] = mfma16(al, b2h[ks], acc2[m]);
            acc2[m] = mfma16(ah, b2l[ks], acc2[m]);
        }
    }
    // relu + write C2 in the phase-C layout (wave-private slice)
#pragma unroll
    for (int m = 0; m < 4; ++m) {
        int q = 4 * m + g;
        hb4[nt * 16 + (q ^ l15)] = make_float4(
            fmaxf(acc2[m][0], 0.f), fmaxf(acc2[m][1], 0.f),
            fmaxf(acc2[m][2], 0.f), fmaxf(acc2[m][3], 0.f));
    }

    // ---- phase C: fp16 store + BN partial stats (wave-private reads) ----
    {
        int q = lane & 15;          // channel quad
        int ng = lane >> 4;         // node subgroup
        int base_nt = wv * 16;
        float4 bs = make_float4(0, 0, 0, 0), bq = make_float4(0, 0, 0, 0);
#pragma unroll
        for (int s2 = 0; s2 < 4; ++s2) {
            int nt2 = base_nt + s2 * 4 + ng;
            int n = n0 + nt2;
            if (n < N) {
                float4 v = hb4[nt2 * 16 + (q ^ (nt2 & 15))];
                ushort4 o;
                o.x = f2h(v.x); o.y = f2h(v.y); o.z = f2h(v.z); o.w = f2h(v.w);
                *(ushort4*)(vout + (size_t)n * 64 + q * 4) = o;
                bs.x += v.x; bs.y += v.y; bs.z += v.z; bs.w += v.w;
                bq.x += v.x * v.x; bq.y += v.y * v.y;
                bq.z += v.z * v.z; bq.w += v.w * v.w;
            }
        }
#pragma unroll
        for (int off = 16; off < 64; off <<= 1) {
            bs.x += __shfl_xor(bs.x, off); bs.y += __shfl_xor(bs.y, off);
            bs.z += __shfl_xor(bs.z, off); bs.w += __shfl_xor(bs.w, off);
            bq.x += __shfl_xor(bq.x, off); bq.y += __shfl_xor(bq.y, off);
            bq.z += __shfl_xor(bq.z, off); bq.w += __shfl_xor(bq.w, off);
        }
        if (ng == 0) { bnS[wv][q] = bs; bnQ[wv][q] = bq; }
        __syncthreads();
        if (tid < 16) {
            float4 s4 = bnS[0][tid], q4 = bnQ[0][tid];
#pragma unroll
            for (int w2 = 1; w2 < 4; ++w2) {
                float4 t = bnS[w2][tid];
                s4.x += t.x; s4.y += t.y; s4.z += t.z; s4.w += t.w;
                float4 u = bnQ[w2][tid];
                q4.x += u.x; q4.y += u.y; q4.z += u.z; q4.w += u.w;
            }
            float* bkt = bnpart + (blockIdx.x & 31) * 128;
            atomicAdd(&bkt[tid * 4 + 0], s4.x);
            atomicAdd(&bkt[tid * 4 + 1], s4.y);
            atomicAdd(&bkt[tid * 4 + 2], s4.z);
            atomicAdd(&bkt[tid * 4 + 3], s4.w);
            atomicAdd(&bkt[64 + tid * 4 + 0], q4.x);
            atomicAdd(&bkt[64 + tid * 4 + 1], q4.y);
            atomicAdd(&bkt[64 + tid * 4 + 2], q4.z);
            atomicAdd(&bkt[64 + tid * 4 + 3], q4.w);
        }
    }
}

// Graph pooling (contiguous segment-sum, zero atomics) + BN finalize.
__global__ __launch_bounds__(256) void k_pool_bn(
        const unsigned short* __restrict__ vb, const int* __restrict__ gstart,
        float* __restrict__ Sg,
        const float* __restrict__ bnpart, const float* __restrict__ gamma,
        const float* __restrict__ beta, float* __restrict__ a_out,
        float* __restrict__ b_out, int N, int Gn, int nbp) {
    if ((int)blockIdx.x == nbp) {
        int c = threadIdx.x;
        if (c < 64) {
            float s = 0.f, q = 0.f;
            for (int i = 0; i < 32; ++i) {
                s += bnpart[i * 128 + c];
                q += bnpart[i * 128 + 64 + c];
            }
            float invN = 1.0f / (float)N;
            float mu = s * invN;
            float var = q * invN - mu * mu;
            float ac = gamma[c] * rsqrtf(var + 1e-5f);
            a_out[c] = ac;
            b_out[c] = beta[c] - mu * ac;
        }
        return;
    }
    int lane = threadIdx.x & 63, wv = threadIdx.x >> 6;
    int g = blockIdx.x * 4 + wv;
    if (g >= Gn) return;
    int sub = lane >> 4, q = lane & 15;
    int s = gstart[g], e = gstart[g + 1];
    float4 a0 = make_float4(0, 0, 0, 0), a1 = make_float4(0, 0, 0, 0);
    float4 a2 = make_float4(0, 0, 0, 0), a3 = make_float4(0, 0, 0, 0);
    int eb = s;
    for (; eb + 16 <= e; eb += 16) {
        ushort4 u0 = *(const ushort4*)(vb + (size_t)(eb + 0 + sub) * 64 + q * 4);
        ushort4 u1 = *(const ushort4*)(vb + (size_t)(eb + 4 + sub) * 64 + q * 4);
        ushort4 u2 = *(const ushort4*)(vb + (size_t)(eb + 8 + sub) * 64 + q * 4);
        ushort4 u3 = *(const ushort4*)(vb + (size_t)(eb + 12 + sub) * 64 + q * 4);
        a0.x += h2f(u0.x); a0.y += h2f(u0.y); a0.z += h2f(u0.z); a0.w += h2f(u0.w);
        a1.x += h2f(u1.x); a1.y += h2f(u1.y); a1.z += h2f(u1.z); a1.w += h2f(u1.w);
        a2.x += h2f(u2.x); a2.y += h2f(u2.y); a2.z += h2f(u2.z); a2.w += h2f(u2.w);
        a3.x += h2f(u3.x); a3.y += h2f(u3.y); a3.z += h2f(u3.z); a3.w += h2f(u3.w);
    }
    for (; eb + 4 <= e; eb += 4) {
        ushort4 u0 = *(const ushort4*)(vb + (size_t)(eb + sub) * 64 + q * 4);
        a0.x += h2f(u0.x); a0.y += h2f(u0.y); a0.z += h2f(u0.z); a0.w += h2f(u0.w);
    }
    if (eb + sub < e) {
        ushort4 u0 = *(const ushort4*)(vb + (size_t)(eb + sub) * 64 + q * 4);
        a1.x += h2f(u0.x); a1.y += h2f(u0.y); a1.z += h2f(u0.z); a1.w += h2f(u0.w);
    }
    float4 t;
    t.x = (a0.x + a1.x) + (a2.x + a3.x);
    t.y = (a0.y + a1.y) + (a2.y + a3.y);
    t.z = (a0.z + a1.z) + (a2.z + a3.z);
    t.w = (a0.w + a1.w) + (a2.w + a3.w);
#pragma unroll
    for (int off = 16; off < 64; off <<= 1) {
        t.x += __shfl_xor(t.x, off); t.y += __shfl_xor(t.y, off);
        t.z += __shfl_xor(t.z, off); t.w += __shfl_xor(t.w, off);
    }
    if (sub == 0) {
        *(float4*)(Sg + (size_t)g * 64 + q * 4) = t;
    }
}

// Head: z[g,320] = concat_l (a_l*S_l[g] + b_l*cnt[g]); out = relu(z@fc1+b)@fc2+b
__global__ __launch_bounds__(256) void k_final(
        const float* __restrict__ S, const float* __restrict__ ab,
        const int* __restrict__ cntg,
        const float* __restrict__ fc1W, const float* __restrict__ fc1b,
        const float* __restrict__ fc2W, const float* __restrict__ fc2b,
        float* __restrict__ out, int G) {
    __shared__ float zbuf[4][320];
    int tid = threadIdx.x;
    int lane = tid & 63, wv = tid >> 6;
    int g = blockIdx.x * 4 + wv;
    if (g >= G) return;
    float cf = (float)cntg[g];
#pragma unroll
    for (int l = 0; l < 5; ++l) {
        float a = ab[l * 128 + lane];
        float b = ab[l * 128 + 64 + lane];
        zbuf[wv][l * 64 + lane] = a * S[((size_t)l * G + g) * 64 + lane] + b * cf;
    }
    float acc = fc1b[lane];
    for (int k = 0; k < 320; ++k) acc += zbuf[wv][k] * fc1W[k * 64 + lane];
    float t = fmaxf(acc, 0.f);
    float r = t * fc2W[lane];
#pragma unroll
    for (int off = 32; off >= 1; off >>= 1) r += __shfl_xor(r, off);
    if (lane == 0) out[g] = r + fc2b[0];
}

extern "C" void kernel_launch(void* const* d_in, const int* in_sizes, int n_in,
                              void* d_out, int out_size, void* d_ws, size_t ws_size,
                              hipStream_t stream) {
    const float* x    = (const float*)d_in[0];
    const int*   ei   = (const int*)d_in[1];
    const int*   batch= (const int*)d_in[2];
    const float* W1a  = (const float*)d_in[3];
    const float* b1a  = (const float*)d_in[4];
    const float* W1b  = (const float*)d_in[5];
    const float* b1b  = (const float*)d_in[6];
    const float* Wa   = (const float*)d_in[7];
    const float* ba   = (const float*)d_in[8];
    const float* Wb   = (const float*)d_in[9];
    const float* bb   = (const float*)d_in[10];
    const float* gamma= (const float*)d_in[11];
    const float* beta = (const float*)d_in[12];
    const float* fc1W = (const float*)d_in[13];
    const float* fc1b = (const float*)d_in[14];
    const float* fc2W = (const float*)d_in[15];
    const float* fc2b = (const float*)d_in[16];

    const int N = in_sizes[2];
    const int E = in_sizes[1] / 2;
    const int G = out_size;
    const int* srcp = ei;
    const int* dstp = ei + E;

    char* p = (char*)d_ws;
    auto alloc = [&](size_t bytes) {
        char* r = p;
        p += (bytes + 255) & ~size_t(255);
        return r;
    };
    unsigned short* aggh = (unsigned short*)alloc((size_t)N * 64 * 2);
    unsigned short* vb   = (unsigned short*)alloc((size_t)N * 64 * 2);
    int*   col    = (int*)  alloc((size_t)E * 4);
    int*   rank_  = (int*)  alloc((size_t)E * 4);
    int*   rp     = (int*)  alloc((size_t)(N + 1) * 4);
    unsigned short* x16h = (unsigned short*)alloc((size_t)N * 16 * 2);
    float* h16    = (float*)alloc((size_t)N * 16 * 4);
    int*   bsum   = (int*)  alloc(512);
    int*   boffs  = (int*)  alloc(512);
    int*   gstart = (int*)  alloc((size_t)(G + 1) * 4);
    float* ab     = (float*)alloc(5 * 128 * 4);
    half_t* wfrag = (half_t*)alloc((size_t)10 * 8192 * 2);
    // ---- zeroed region (single memset) ----
    char*  z0     = p;
    int*   cntn   = (int*)  alloc((size_t)N * 4);
    int*   cntg   = (int*)  alloc((size_t)G * 4);
    float* S      = (float*)alloc((size_t)5 * G * 64 * 4);
    float* bnpart = (float*)alloc((size_t)5 * 32 * 128 * 4);
    size_t zbytes = (size_t)(p - z0);

    hipMemsetAsync(z0, 0, zbytes, stream);

    int nb_e = (E + 255) / 256;
    int nb_n = (N + 255) / 256;
    int nb_scan = (N + SCAN_ELEMS - 1) / SCAN_ELEMS;
    k_wprep<<<10, 256, 0, stream>>>(W1a, W1b, Wa, Wb, wfrag);
    k_hist<<<nb_e, 256, 0, stream>>>(dstp, E, cntn, rank_);
    k_prep<<<nb_n, 256, 0, stream>>>(x, x16h, batch, cntg, N);
    k_scan1<<<nb_scan, 256, 0, stream>>>(cntn, N, rp, bsum);
    k_scan2g<<<2, 256, 0, stream>>>(bsum, nb_scan, boffs, cntg, G, gstart);
    k_scan3<<<(N + 255) / 256, 256, 0, stream>>>(rp, N, boffs, E);
    k_fill<<<nb_e, 256, 0, stream>>>(srcp, dstp, rank_, E, rp, col);

    int nb_node = (N + 3) / 4;
    int nb_tile = (N + 63) / 64;
    int nbp = (G + 3) / 4;
    const size_t FR = 8192;   // halfs per packed matrix

    // Layer 1: 16-dim fp16 gather, then mlp<FIRST> does W1a from h16 (fp32)
    k_gather16<<<nb_node, 256, 0, stream>>>(x16h, h16, rp, col, N);
    k_mlp<true><<<nb_tile, 256, 0, stream>>>(h16, vb,
        wfrag + 0 * FR, b1a, wfrag + 1 * FR, b1b, bnpart, N);
    k_pool_bn<<<nbp + 1, 256, 0, stream>>>(vb, gstart, S, bnpart,
        gamma, beta, ab, ab + 64, N, G, nbp);

    for (int l = 0; l < 4; ++l) {
        k_gather<<<nb_node, 256, 0, stream>>>(vb, aggh, rp, col,
            ab + l * 128, N);
        k_mlp<false><<<nb_tile, 256, 0, stream>>>(aggh, vb,
            wfrag + (size_t)(2 + l) * FR, ba + l * 64,
            wfrag + (size_t)(6 + l) * FR, bb + l * 64,
            bnpart + (size_t)(l + 1) * 32 * 128, N);
        k_pool_bn<<<nbp + 1, 256, 0, stream>>>(vb, gstart,
            S + (size_t)(l + 1) * G * 64,
            bnpart + (size_t)(l + 1) * 32 * 128,
            gamma + (l + 1) * 64, beta + (l + 1) * 64,
            ab + (l + 1) * 128, ab + (l + 1) * 128 + 64, N, G, nbp);
    }

    k_final<<<(G + 3) / 4, 256, 0, stream>>>(S, ab, cntg, fc1W, fc1b, fc2W, fc2b,
                                             (float*)d_out, G);
}